// Round 1
// baseline (153.143 us; speedup 1.0000x reference)
//
#include <hip/hip_runtime.h>
#include <stdint.h>

#define NN 8192
#define FIN 512
#define FOUT 64
#define ALPHA 0.2f

typedef float f32x4 __attribute__((ext_vector_type(4)));
typedef int   i32x4 __attribute__((ext_vector_type(4)));
typedef short bf16x8 __attribute__((ext_vector_type(8)));

__device__ __forceinline__ unsigned short f2bf(float f) {
  union { float f; unsigned u; } v; v.f = f;
  unsigned r = (v.u + 0x7fffu + ((v.u >> 16) & 1u)) >> 16;
  return (unsigned short)r;
}

// ---------------- Phase 1: h = x@W (fp32), f1 = h@a1, f2 = h@a2, ht = bf16(h)^T -------------
// 1024 waves, each computes 8 rows x 64 cols. lane = output col.
__global__ __launch_bounds__(256) void prep_kernel(
    const float* __restrict__ x, const float* __restrict__ W,
    const float* __restrict__ a, unsigned short* __restrict__ ht,
    float* __restrict__ f1, float* __restrict__ f2) {
  const int lane = threadIdx.x & 63;
  const int g = blockIdx.x * 4 + (threadIdx.x >> 6);  // wave id 0..1023
  const int i0 = g * 8;

  float acc[8];
#pragma unroll
  for (int r = 0; r < 8; ++r) acc[r] = 0.0f;

  for (int k = 0; k < FIN; k += 4) {
    float w0 = W[(k + 0) * FOUT + lane];
    float w1 = W[(k + 1) * FOUT + lane];
    float w2 = W[(k + 2) * FOUT + lane];
    float w3 = W[(k + 3) * FOUT + lane];
#pragma unroll
    for (int r = 0; r < 8; ++r) {
      f32x4 xv = *(const f32x4*)(x + (size_t)(i0 + r) * FIN + k);
      acc[r] = fmaf(xv[0], w0, acc[r]);
      acc[r] = fmaf(xv[1], w1, acc[r]);
      acc[r] = fmaf(xv[2], w2, acc[r]);
      acc[r] = fmaf(xv[3], w3, acc[r]);
    }
  }

  // f1 / f2: full-wave reductions (64 cols)
  const float a1c = a[lane];
  const float a2c = a[FOUT + lane];
#pragma unroll
  for (int r = 0; r < 8; ++r) {
    float p1 = acc[r] * a1c;
    float p2 = acc[r] * a2c;
#pragma unroll
    for (int off = 32; off >= 1; off >>= 1) {
      p1 += __shfl_xor(p1, off, 64);
      p2 += __shfl_xor(p2, off, 64);
    }
    if (lane == 0) { f1[i0 + r] = p1; f2[i0 + r] = p2; }
  }

  // ht[c][i0..i0+7] — contiguous 16B per lane
  unsigned short hs[8];
#pragma unroll
  for (int r = 0; r < 8; ++r) hs[r] = f2bf(acc[r]);
  *(uint4*)(ht + (size_t)lane * NN + i0) = *(uint4*)hs;
}

// ---------------- Phase 2: fused mask + softmax(unnormalized) + PV (MFMA) + elu -------------
// One block (8 waves) per 16 output rows. Wave wv handles j in [wv*1024, (wv+1)*1024).
__global__ __launch_bounds__(512) void attn_kernel(
    const int* __restrict__ adj, const unsigned short* __restrict__ ht,
    const float* __restrict__ f1, const float* __restrict__ f2,
    float* __restrict__ out) {
  __shared__ float lds_num[8][16][64];
  __shared__ float lds_den[8][16];

  const int tid = threadIdx.x;
  const int lane = tid & 63;
  const int wv = tid >> 6;     // 0..7
  const int rg = blockIdx.x;   // 0..511
  const int r15 = lane & 15;
  const int kgrp = lane >> 4;  // 0..3
  const int row = rg * 16 + r15;

  const float f1v = f1[row];
  const int* adjrow = adj + (size_t)row * NN;
  const int jbase = wv * 1024 + kgrp * 8;

  f32x4 acc0 = {0.f, 0.f, 0.f, 0.f};
  f32x4 acc1 = acc0, acc2 = acc0, acc3 = acc0;
  float den = 0.0f;

  // prefetch t=0
  i32x4 aA = *(const i32x4*)(adjrow + jbase);
  i32x4 aB = *(const i32x4*)(adjrow + jbase + 4);
  f32x4 fA = *(const f32x4*)(f2 + jbase);
  f32x4 fB = *(const f32x4*)(f2 + jbase + 4);

  for (int t = 0; t < 32; ++t) {
    const int jl = jbase + t * 32;
    const int jn = jbase + ((t + 1) & 31) * 32;  // wraps at end (dummy reload, in-bounds)

    i32x4 naA = *(const i32x4*)(adjrow + jn);
    i32x4 naB = *(const i32x4*)(adjrow + jn + 4);
    f32x4 nfA = *(const f32x4*)(f2 + jn);
    f32x4 nfB = *(const f32x4*)(f2 + jn + 4);

    float w[8];
#pragma unroll
    for (int e = 0; e < 4; ++e) {
      float s = f1v + fA[e];
      float l = fmaxf(s, ALPHA * s);
      float ev = __expf(l);
      w[e] = (aA[e] > 0) ? ev : 0.0f;
    }
#pragma unroll
    for (int e = 0; e < 4; ++e) {
      float s = f1v + fB[e];
      float l = fmaxf(s, ALPHA * s);
      float ev = __expf(l);
      w[4 + e] = (aB[e] > 0) ? ev : 0.0f;
    }
    den += ((w[0] + w[1]) + (w[2] + w[3])) + ((w[4] + w[5]) + (w[6] + w[7]));

    union { unsigned short us[8]; bf16x8 v; } pk;
#pragma unroll
    for (int e = 0; e < 8; ++e) pk.us[e] = f2bf(w[e]);

    bf16x8 b0 = *(const bf16x8*)(ht + (size_t)(0 * 16 + r15) * NN + jl);
    bf16x8 b1 = *(const bf16x8*)(ht + (size_t)(1 * 16 + r15) * NN + jl);
    bf16x8 b2 = *(const bf16x8*)(ht + (size_t)(2 * 16 + r15) * NN + jl);
    bf16x8 b3 = *(const bf16x8*)(ht + (size_t)(3 * 16 + r15) * NN + jl);

    acc0 = __builtin_amdgcn_mfma_f32_16x16x32_bf16(pk.v, b0, acc0, 0, 0, 0);
    acc1 = __builtin_amdgcn_mfma_f32_16x16x32_bf16(pk.v, b1, acc1, 0, 0, 0);
    acc2 = __builtin_amdgcn_mfma_f32_16x16x32_bf16(pk.v, b2, acc2, 0, 0, 0);
    acc3 = __builtin_amdgcn_mfma_f32_16x16x32_bf16(pk.v, b3, acc3, 0, 0, 0);

    aA = naA; aB = naB; fA = nfA; fB = nfB;
  }

  // full denominator for row r15 within this wave's j-range
  den += __shfl_xor(den, 16, 64);
  den += __shfl_xor(den, 32, 64);

  // write partials to LDS. C layout: row_local = kgrp*4 + reg, col = cb*16 + r15
#pragma unroll
  for (int r = 0; r < 4; ++r) {
    lds_num[wv][kgrp * 4 + r][0 * 16 + r15] = acc0[r];
    lds_num[wv][kgrp * 4 + r][1 * 16 + r15] = acc1[r];
    lds_num[wv][kgrp * 4 + r][2 * 16 + r15] = acc2[r];
    lds_num[wv][kgrp * 4 + r][3 * 16 + r15] = acc3[r];
  }
  if (lane < 16) lds_den[wv][lane] = den;
  __syncthreads();

  // combine 8 waves, divide, elu, store
  for (int idx = tid; idx < 16 * 64; idx += 512) {
    const int orow = idx >> 6;
    const int ocol = idx & 63;
    float s = 0.0f, d = 0.0f;
#pragma unroll
    for (int w2 = 0; w2 < 8; ++w2) {
      s += lds_num[w2][orow][ocol];
      d += lds_den[w2][orow];
    }
    float v = s / d;
    out[(size_t)(rg * 16 + orow) * FOUT + ocol] = (v > 0.0f) ? v : (__expf(v) - 1.0f);
  }
}

extern "C" void kernel_launch(void* const* d_in, const int* in_sizes, int n_in,
                              void* d_out, int out_size, void* d_ws, size_t ws_size,
                              hipStream_t stream) {
  const float* x = (const float*)d_in[0];
  const int* adj = (const int*)d_in[1];
  const float* W = (const float*)d_in[2];
  const float* a = (const float*)d_in[3];
  float* out = (float*)d_out;

  char* ws = (char*)d_ws;
  unsigned short* ht = (unsigned short*)ws;                    // 64*8192*2 = 1 MB
  float* f1 = (float*)(ws + (size_t)FOUT * NN * 2);            // 32 KB
  float* f2 = f1 + NN;                                         // 32 KB

  hipLaunchKernelGGL(prep_kernel, dim3(256), dim3(256), 0, stream, x, W, a, ht, f1, f2);
  hipLaunchKernelGGL(attn_kernel, dim3(512), dim3(512), 0, stream, adj, ht, f1, f2, out);
}